// Round 1
// baseline (80.732 us; speedup 1.0000x reference)
//
#include <hip/hip_runtime.h>

// FFMCell combine: out = state * exp((-|a| + i*b) * j) + x, elementwise over
// [T=4096, TRACE=64, CTX=64]; third output = j + i (per-t ints, stored as f32).
// Memory-bound: ~403 MB of HBM traffic -> target ~64us at 6.3 TB/s.

constexpr int T_DIM = 4096;
constexpr int TRACE = 64;
constexpr int CTX   = 64;
constexpr int N     = T_DIM * TRACE * CTX;   // 16,777,216 elements per array
constexpr int N4    = N / 4;                 // float4 work items

__global__ __launch_bounds__(256) void ffm_kernel(
    const float* __restrict__ a,
    const float* __restrict__ b,
    const float* __restrict__ s_re,
    const float* __restrict__ s_im,
    const float* __restrict__ x_re,
    const float* __restrict__ x_im,
    const int*   __restrict__ iv,
    const int*   __restrict__ jv,
    float* __restrict__ out)
{
    const int gtid   = blockIdx.x * blockDim.x + threadIdx.x;
    const int stride = gridDim.x * blockDim.x;

    // Third output: (j + i) as float, T elements at offset 2*N.
    for (int t = gtid; t < T_DIM; t += stride) {
        out[2 * N + t] = (float)(jv[t] + iv[t]);
    }

    for (int idx = gtid; idx < N4; idx += stride) {
        const int t   = idx >> 10;        // / (TRACE*CTX/4 = 1024)
        const int rem = idx & 1023;
        const int m   = rem >> 4;         // / (CTX/4 = 16)
        const int c4  = (rem & 15) << 2;  // ctx offset of this float4

        const float tj    = (float)jv[t];
        const float decay = __expf(-fabsf(a[m]) * tj);

        const float4 bv  = *reinterpret_cast<const float4*>(b + c4);
        const int   base = idx << 2;
        const float4 sre = *reinterpret_cast<const float4*>(s_re + base);
        const float4 sim = *reinterpret_cast<const float4*>(s_im + base);
        const float4 xre = *reinterpret_cast<const float4*>(x_re + base);
        const float4 xim = *reinterpret_cast<const float4*>(x_im + base);

        float4 ore, oim;
        const float* bp  = reinterpret_cast<const float*>(&bv);
        const float* srp = reinterpret_cast<const float*>(&sre);
        const float* sip = reinterpret_cast<const float*>(&sim);
        const float* xrp = reinterpret_cast<const float*>(&xre);
        const float* xip = reinterpret_cast<const float*>(&xim);
        float* orp = reinterpret_cast<float*>(&ore);
        float* oip = reinterpret_cast<float*>(&oim);

        #pragma unroll
        for (int k = 0; k < 4; ++k) {
            float s, c;
            __sincosf(bp[k] * tj, &s, &c);
            const float gre = decay * c;
            const float gim = decay * s;
            const float sr  = srp[k];
            const float si  = sip[k];
            orp[k] = fmaf(sr, gre, fmaf(-si, gim, xrp[k]));
            oip[k] = fmaf(sr, gim, fmaf( si, gre, xip[k]));
        }

        *reinterpret_cast<float4*>(out + base)     = ore;
        *reinterpret_cast<float4*>(out + N + base) = oim;
    }
}

extern "C" void kernel_launch(void* const* d_in, const int* in_sizes, int n_in,
                              void* d_out, int out_size, void* d_ws, size_t ws_size,
                              hipStream_t stream) {
    const float* a    = (const float*)d_in[0];
    const float* b    = (const float*)d_in[1];
    const float* s_re = (const float*)d_in[2];
    const float* s_im = (const float*)d_in[3];
    const float* x_re = (const float*)d_in[4];
    const float* x_im = (const float*)d_in[5];
    const int*   iv   = (const int*)d_in[6];
    const int*   jv   = (const int*)d_in[7];
    float* out = (float*)d_out;

    const int block = 256;
    const int grid  = 2048;   // grid-stride: 8 float4 items per thread
    ffm_kernel<<<grid, block, 0, stream>>>(a, b, s_re, s_im, x_re, x_im, iv, jv, out);
}

// Round 3
// 78.174 us; speedup vs baseline: 1.0327x; 1.0327x over previous
//
#include <hip/hip_runtime.h>

// FFMCell combine: out = state * exp((-|a| + i*b) * j) + x, elementwise over
// [T=4096, TRACE=64, CTX=64]; third output = j + i (per-t ints, stored as f32).
// Memory-bound. R1 was latency-bound (VGPR=20, 64B in flight/wave-iter,
// 3.3 TB/s). R3: 32B/thread/iter => 8 independent 16B loads in flight,
// non-temporal stores (via clang ext_vector to satisfy the builtin) so the
// output stream doesn't evict cached inputs.

typedef float f32x4 __attribute__((ext_vector_type(4)));

constexpr int T_DIM = 4096;
constexpr int TRACE = 64;
constexpr int CTX   = 64;
constexpr int N     = T_DIM * TRACE * CTX;   // 16,777,216 elements per array
constexpr int N8    = N / 8;                 // 2,097,152 8-float work items

__global__ __launch_bounds__(256) void ffm_kernel(
    const float* __restrict__ a,
    const float* __restrict__ b,
    const float* __restrict__ s_re,
    const float* __restrict__ s_im,
    const float* __restrict__ x_re,
    const float* __restrict__ x_im,
    const int*   __restrict__ iv,
    const int*   __restrict__ jv,
    float* __restrict__ out)
{
    const int gtid   = blockIdx.x * blockDim.x + threadIdx.x;
    const int stride = gridDim.x * blockDim.x;   // 524288 -> exactly 4 trips

    // Third output: (j + i) as float, T elements at offset 2*N.
    for (int t = gtid; t < T_DIM; t += stride) {
        out[2 * N + t] = (float)(jv[t] + iv[t]);
    }

    for (int idx = gtid; idx < N8; idx += stride) {
        const int base = idx << 3;            // element offset, 8-aligned
        const int t    = base >> 12;          // / (TRACE*CTX)
        const int m    = (base >> 6) & 63;    // trace index (8 elems never cross m)
        const int c8   = base & 63;           // ctx offset of this 8-chunk

        const float tj    = (float)jv[t];
        const float decay = __expf(-fabsf(a[m]) * tj);

        // Issue all 10 loads up front; compiler schedules them together.
        const f32x4 bv0 = *reinterpret_cast<const f32x4*>(b + c8);
        const f32x4 bv1 = *reinterpret_cast<const f32x4*>(b + c8 + 4);
        const f32x4 sr0 = *reinterpret_cast<const f32x4*>(s_re + base);
        const f32x4 sr1 = *reinterpret_cast<const f32x4*>(s_re + base + 4);
        const f32x4 si0 = *reinterpret_cast<const f32x4*>(s_im + base);
        const f32x4 si1 = *reinterpret_cast<const f32x4*>(s_im + base + 4);
        const f32x4 xr0 = *reinterpret_cast<const f32x4*>(x_re + base);
        const f32x4 xr1 = *reinterpret_cast<const f32x4*>(x_re + base + 4);
        const f32x4 xi0 = *reinterpret_cast<const f32x4*>(x_im + base);
        const f32x4 xi1 = *reinterpret_cast<const f32x4*>(x_im + base + 4);

        f32x4 or0, or1, oi0, oi1;

        #pragma unroll
        for (int k = 0; k < 4; ++k) {
            float s, c;
            __sincosf(bv0[k] * tj, &s, &c);
            const float gre = decay * c;
            const float gim = decay * s;
            or0[k] = fmaf(sr0[k], gre, fmaf(-si0[k], gim, xr0[k]));
            oi0[k] = fmaf(sr0[k], gim, fmaf( si0[k], gre, xi0[k]));
        }
        #pragma unroll
        for (int k = 0; k < 4; ++k) {
            float s, c;
            __sincosf(bv1[k] * tj, &s, &c);
            const float gre = decay * c;
            const float gim = decay * s;
            or1[k] = fmaf(sr1[k], gre, fmaf(-si1[k], gim, xr1[k]));
            oi1[k] = fmaf(sr1[k], gim, fmaf( si1[k], gre, xi1[k]));
        }

        // Non-temporal: outputs are never re-read; don't evict cached inputs.
        __builtin_nontemporal_store(or0, reinterpret_cast<f32x4*>(out + base));
        __builtin_nontemporal_store(or1, reinterpret_cast<f32x4*>(out + base + 4));
        __builtin_nontemporal_store(oi0, reinterpret_cast<f32x4*>(out + N + base));
        __builtin_nontemporal_store(oi1, reinterpret_cast<f32x4*>(out + N + base + 4));
    }
}

extern "C" void kernel_launch(void* const* d_in, const int* in_sizes, int n_in,
                              void* d_out, int out_size, void* d_ws, size_t ws_size,
                              hipStream_t stream) {
    const float* a    = (const float*)d_in[0];
    const float* b    = (const float*)d_in[1];
    const float* s_re = (const float*)d_in[2];
    const float* s_im = (const float*)d_in[3];
    const float* x_re = (const float*)d_in[4];
    const float* x_im = (const float*)d_in[5];
    const int*   iv   = (const int*)d_in[6];
    const int*   jv   = (const int*)d_in[7];
    float* out = (float*)d_out;

    const int block = 256;
    const int grid  = 2048;   // 8 blocks/CU; 4 outer-loop trips/thread
    ffm_kernel<<<grid, block, 0, stream>>>(a, b, s_re, s_im, x_re, x_im, iv, jv, out);
}